// Round 5
// baseline (306.051 us; speedup 1.0000x reference)
//
#include <hip/hip_runtime.h>

#define NN 20000
#define IN_DIM 256
#define HID 128
#define OUT_DIM 64
#define N_LAYERS 4
#define N_PATHS 8
#define PATH_LEN 8
#define N_TYPES 2

typedef __attribute__((ext_vector_type(8))) short bf16x8;
typedef __attribute__((ext_vector_type(4))) float f32x4;

__device__ __forceinline__ float bf2f(ushort u) {
    union { uint u; float f; } c; c.u = ((uint)u) << 16; return c.f;
}
__device__ __forceinline__ ushort f2bf(float f) {
    union { float f; uint u; } c; c.f = f;
    uint u = c.u;
    uint lsb = (u >> 16) & 1;
    u += 0x7fffu + lsb;          // round-to-nearest-even (inputs finite)
    return (ushort)(u >> 16);
}

// ---------------------------------------------------------------------------
// One-shot fp32 -> bf16 conversion of all weight matrices (quad-per-thread).
// ---------------------------------------------------------------------------
__global__ __launch_bounds__(256) void cvt_weights(
    const float* __restrict__ w_in, const float* __restrict__ w_layer,
    const float* __restrict__ w_out,
    ushort* __restrict__ o_in, ushort* __restrict__ o_layer,
    ushort* __restrict__ o_out)
{
    int i = blockIdx.x * 256 + threadIdx.x;
    const float* s; ushort* d; int off;
    if (i < 8192)        { s = w_in;    d = o_in;    off = i; }
    else if (i < 40960)  { s = w_layer; d = o_layer; off = i - 8192; }
    else if (i < 43008)  { s = w_out;   d = o_out;   off = i - 40960; }
    else return;
    float4 v = ((const float4*)s)[off];
    ushort4 o;
    o.x = f2bf(v.x); o.y = f2bf(v.y); o.z = f2bf(v.z); o.w = f2bf(v.w);
    ((ushort4*)d)[off] = o;
}

// ---------------------------------------------------------------------------
// bf16 MFMA GEMM (proven): C = epilogue(A[M,K] @ W[N,K]^T), fp32 accumulate.
// BM=64, BK=64, 4 waves (2x2). LDS XOR-swizzle (T2). Used for fc_in / fc_out.
// EPI 0: bf16 out = relu(acc + bias[n]);  EPI 2: f32 out = relu(acc + bias[n])
// ---------------------------------------------------------------------------
template <int N, int K, int EPI, bool AF32>
__global__ __launch_bounds__(256) void gemm_mfma(
    const void* __restrict__ Ap,
    const ushort* __restrict__ W,     // [N][K] bf16
    const float* __restrict__ bias,
    void* __restrict__ Cout,
    int M)
{
    constexpr int BM = 64, BK = 64;
    constexpr int NC = N / 32;

    __shared__ short As[BM * BK];
    __shared__ short Ws[N * BK];

    const int tid = threadIdx.x;
    const int lane = tid & 63;
    const int w = tid >> 6;
    const int wr = w >> 1, wc = w & 1;
    const int m0 = blockIdx.x * BM;
    const int l15 = lane & 15, l4 = lane >> 4;

    f32x4 acc[2][NC];
#pragma unroll
    for (int mr = 0; mr < 2; ++mr)
#pragma unroll
        for (int nc = 0; nc < NC; ++nc)
#pragma unroll
            for (int j = 0; j < 4; ++j) acc[mr][nc][j] = 0.f;

    for (int k0 = 0; k0 < K; k0 += BK) {
#pragma unroll
        for (int c = tid; c < BM * BK / 8; c += 256) {
            int r = c >> 3, kc = c & 7;
            int gr = m0 + r; if (gr >= M) gr = M - 1;
            bf16x8 v;
            if constexpr (AF32) {
                const float* Af = (const float*)Ap;
                float4 v0 = *(const float4*)(Af + (long)gr * K + k0 + kc * 8);
                float4 v1 = *(const float4*)(Af + (long)gr * K + k0 + kc * 8 + 4);
                v[0] = (short)f2bf(v0.x); v[1] = (short)f2bf(v0.y);
                v[2] = (short)f2bf(v0.z); v[3] = (short)f2bf(v0.w);
                v[4] = (short)f2bf(v1.x); v[5] = (short)f2bf(v1.y);
                v[6] = (short)f2bf(v1.z); v[7] = (short)f2bf(v1.w);
            } else {
                v = *(const bf16x8*)((const ushort*)Ap + (long)gr * K + k0 + kc * 8);
            }
            int di = (r * BK + kc * 8) ^ ((r & 7) << 3);
            *(bf16x8*)&As[di] = v;
        }
#pragma unroll
        for (int c = tid; c < N * BK / 8; c += 256) {
            int r = c >> 3, kc = c & 7;
            bf16x8 v = *(const bf16x8*)(W + (long)r * K + k0 + kc * 8);
            int di = (r * BK + kc * 8) ^ ((r & 7) << 3);
            *(bf16x8*)&Ws[di] = v;
        }
        __syncthreads();

#pragma unroll
        for (int ks = 0; ks < 2; ++ks) {
            bf16x8 av[2], bv[NC];
            const int kk = ks * 32 + l4 * 8;
#pragma unroll
            for (int mr = 0; mr < 2; ++mr) {
                int r = wr * 32 + mr * 16 + l15;
                av[mr] = *(const bf16x8*)&As[(r * BK + kk) ^ ((r & 7) << 3)];
            }
#pragma unroll
            for (int nc = 0; nc < NC; ++nc) {
                int r = wc * (N / 2) + nc * 16 + l15;
                bv[nc] = *(const bf16x8*)&Ws[(r * BK + kk) ^ ((r & 7) << 3)];
            }
#pragma unroll
            for (int mr = 0; mr < 2; ++mr)
#pragma unroll
                for (int nc = 0; nc < NC; ++nc)
                    acc[mr][nc] = __builtin_amdgcn_mfma_f32_16x16x32_bf16(
                        av[mr], bv[nc], acc[mr][nc], 0, 0, 0);
        }
        __syncthreads();
    }

#pragma unroll
    for (int mr = 0; mr < 2; ++mr) {
#pragma unroll
        for (int nc = 0; nc < NC; ++nc) {
            int gn = wc * (N / 2) + nc * 16 + l15;
#pragma unroll
            for (int j = 0; j < 4; ++j) {
                int gm = m0 + wr * 32 + mr * 16 + l4 * 4 + j;
                if (gm >= M) continue;
                float v = acc[mr][nc][j] + bias[gn];
                v = fmaxf(v, 0.f);
                if (EPI == 0) ((ushort*)Cout)[(long)gm * N + gn] = f2bf(v);
                else          ((float*)Cout)[(long)gm * N + gn] = v;
            }
        }
    }
}

// ---------------------------------------------------------------------------
// FUSED layer: gather + weighted path-mean -> LDS P-tile -> MFMA GEMM ->
// residual epilogue. Block = 512 threads, 16 nodes.
// Phase 1: thread = (node nd = tid>>5, channel-quad ln = tid&31).
//   Path idx read as broadcast int4 from global (no LDS staging / sorting).
//   Type routing by wave-uniform bitmask branch; weights in static registers
//   pre-scaled by 1/count_e. Result written to swizzled LDS Pt[16][256] bf16.
// Phase 2: 8 waves, wave w owns cols [w*16, w*16+16); A from Pt (in LDS
//   already), W staged in BK=64 chunks. 8 MFMAs/wave.
// Epilogue: dst = 0.8*relu(acc) + 0.1*pre + 0.1*in0  (bf16).
// ---------------------------------------------------------------------------
__global__ __launch_bounds__(512) void fused_layer(
    const uint* __restrict__ feats_u,   // src feats [NN][64] (bf16x2)
    const int* __restrict__ paths,      // [P][NN][L]
    const int* __restrict__ ptypes,     // [P]
    const float* __restrict__ pw,       // [2][L][HID] f32
    const ushort* __restrict__ W,       // [HID][2*HID] bf16
    const ushort* __restrict__ pre,     // [NN][HID] bf16 (= src feats)
    const ushort* __restrict__ in0,     // [NN][HID] bf16
    ushort* __restrict__ dst)           // [NN][HID] bf16
{
    __shared__ short Pt[16 * 256];      // 8 KB  (A-tile, swizzled)
    __shared__ short Ws[128 * 64];      // 16 KB (W chunk, swizzled)

    const int tid = threadIdx.x;
    const int nbase = blockIdx.x * 16;

    // ---------------- phase 1: gather ----------------
    {
        const int nd = tid >> 5;        // 0..15
        const int ln = tid & 31;        // channel quad: ch = ln*4
        const int n = nbase + nd;

        uint tmask = 0;
#pragma unroll
        for (int p = 0; p < N_PATHS; ++p) tmask |= (uint)(ptypes[p] != 0) << p;
        const int c1 = __popc(tmask), c0 = N_PATHS - c1;
        const float inv0 = c0 ? 1.f / (float)c0 : 0.f;
        const float inv1 = c1 ? 1.f / (float)c1 : 0.f;

        float4 wv0[PATH_LEN], wv1[PATH_LEN];
#pragma unroll
        for (int l = 0; l < PATH_LEN; ++l) {
            float4 t0 = *(const float4*)&pw[l * HID + ln * 4];
            float4 t1 = *(const float4*)&pw[PATH_LEN * HID + l * HID + ln * 4];
            wv0[l].x = t0.x * inv0; wv0[l].y = t0.y * inv0;
            wv0[l].z = t0.z * inv0; wv0[l].w = t0.w * inv0;
            wv1[l].x = t1.x * inv1; wv1[l].y = t1.y * inv1;
            wv1[l].z = t1.z * inv1; wv1[l].w = t1.w * inv1;
        }

        float4 a0 = {0.f, 0.f, 0.f, 0.f}, a1 = {0.f, 0.f, 0.f, 0.f};

#define GATH_FMA(WV, ACC)                                                   \
        {                                                                   \
            int ia[8] = {i0.x, i0.y, i0.z, i0.w, i1.x, i1.y, i1.z, i1.w};   \
            _Pragma("unroll")                                               \
            for (int l = 0; l < 8; ++l) {                                   \
                uint2 v = *(const uint2*)(feats_u + (long)ia[l] * 64 + ln * 2); \
                ACC.x += bf2f((ushort)(v.x & 0xffff)) * WV[l].x;            \
                ACC.y += bf2f((ushort)(v.x >> 16))    * WV[l].y;            \
                ACC.z += bf2f((ushort)(v.y & 0xffff)) * WV[l].z;            \
                ACC.w += bf2f((ushort)(v.y >> 16))    * WV[l].w;            \
            }                                                               \
        }

#pragma unroll
        for (int p = 0; p < N_PATHS; ++p) {
            const int4* pb = (const int4*)(paths + ((long)p * NN + n) * PATH_LEN);
            int4 i0 = pb[0];            // l = 0..3 (broadcast within node group)
            int4 i1 = pb[1];            // l = 4..7
            if (((tmask >> p) & 1u) == 0u) { GATH_FMA(wv0, a0); }
            else                           { GATH_FMA(wv1, a1); }
        }
#undef GATH_FMA

        // write P-tile (bf16, XOR-swizzled 16B granules within each 512B row)
        uint2 o0, o1;
        o0.x = (uint)f2bf(a0.x) | ((uint)f2bf(a0.y) << 16);
        o0.y = (uint)f2bf(a0.z) | ((uint)f2bf(a0.w) << 16);
        o1.x = (uint)f2bf(a1.x) | ((uint)f2bf(a1.y) << 16);
        o1.y = (uint)f2bf(a1.z) | ((uint)f2bf(a1.w) << 16);
        int e0 = nd * 256 + ln * 4;
        int e1 = nd * 256 + 128 + ln * 4;
        *(uint2*)&Pt[e0 ^ ((nd & 7) << 3)] = o0;
        *(uint2*)&Pt[e1 ^ ((nd & 7) << 3)] = o1;
    }
    __syncthreads();

    // ---------------- phase 2: GEMM (A = Pt, 16 x 256) ----------------
    const int lane = tid & 63;
    const int w = tid >> 6;             // 0..7: column block
    const int l15 = lane & 15, l4 = lane >> 4;

    f32x4 acc = {0.f, 0.f, 0.f, 0.f};

    for (int k0 = 0; k0 < 2 * HID; k0 += 64) {
        // stage W chunk [128][64]
#pragma unroll
        for (int c = tid; c < 128 * 8; c += 512) {
            int r = c >> 3, kc = c & 7;
            bf16x8 v = *(const bf16x8*)(W + (long)r * (2 * HID) + k0 + kc * 8);
            int di = (r * 64 + kc * 8) ^ ((r & 7) << 3);
            *(bf16x8*)&Ws[di] = v;
        }
        __syncthreads();

#pragma unroll
        for (int ks = 0; ks < 2; ++ks) {
            const int kk = ks * 32 + l4 * 8;
            int rA = l15;
            bf16x8 av = *(const bf16x8*)&Pt[(rA * 256 + k0 + kk) ^ ((rA & 7) << 3)];
            int rB = w * 16 + l15;
            bf16x8 bv = *(const bf16x8*)&Ws[(rB * 64 + kk) ^ ((rB & 7) << 3)];
            acc = __builtin_amdgcn_mfma_f32_16x16x32_bf16(av, bv, acc, 0, 0, 0);
        }
        __syncthreads();
    }

    // epilogue: residual mix
    const int gn = w * 16 + l15;
#pragma unroll
    for (int j = 0; j < 4; ++j) {
        int gm = nbase + l4 * 4 + j;
        float v = fmaxf(acc[j], 0.f);
        v = 0.8f * v + 0.1f * bf2f(pre[(long)gm * HID + gn])
                     + 0.1f * bf2f(in0[(long)gm * HID + gn]);
        dst[(long)gm * HID + gn] = f2bf(v);
    }
}

// ---------------------------------------------------------------------------
extern "C" void kernel_launch(void* const* d_in, const int* in_sizes, int n_in,
                              void* d_out, int out_size, void* d_ws, size_t ws_size,
                              hipStream_t stream)
{
    const float* input_x      = (const float*)d_in[0];
    const int*   paths        = (const int*)d_in[1];
    const int*   path_types   = (const int*)d_in[2];
    const float* fc_in_w      = (const float*)d_in[3];
    const float* fc_in_b      = (const float*)d_in[4];
    const float* fc_out_w     = (const float*)d_in[5];
    const float* fc_out_b     = (const float*)d_in[6];
    const float* layer_fc_w   = (const float*)d_in[7];
    const float* path_weights = (const float*)d_in[8];
    float* out = (float*)d_out;

    char* p = (char*)d_ws;
    ushort* w_in     = (ushort*)p; p += HID * IN_DIM * 2;
    ushort* w_layer  = (ushort*)p; p += N_LAYERS * HID * N_TYPES * HID * 2;
    ushort* w_out    = (ushort*)p; p += OUT_DIM * HID * 2;
    ushort* in_feats = (ushort*)p; p += (long)NN * HID * 2;
    ushort* featsA   = (ushort*)p; p += (long)NN * HID * 2;
    ushort* featsB   = (ushort*)p; p += (long)NN * HID * 2;

    cvt_weights<<<168, 256, 0, stream>>>(fc_in_w, layer_fc_w, fc_out_w,
                                         w_in, w_layer, w_out);

    const int GG = (NN + 63) / 64;   // 313

    gemm_mfma<HID, IN_DIM, 0, true><<<GG, 256, 0, stream>>>(
        input_x, w_in, fc_in_b, in_feats, NN);

    const ushort* src = in_feats;
    ushort* dsts[N_LAYERS] = {featsA, featsB, featsA, featsB};
    for (int i = 0; i < N_LAYERS; ++i) {
        fused_layer<<<NN / 16, 512, 0, stream>>>(
            (const uint*)src, paths, path_types,
            path_weights + (long)i * N_TYPES * PATH_LEN * HID,
            w_layer + (long)i * HID * N_TYPES * HID,
            src, in_feats, dsts[i]);
        src = dsts[i];
    }

    gemm_mfma<OUT_DIM, HID, 2, false><<<GG, 256, 0, stream>>>(
        src, w_out, fc_out_b, out, NN);
}